// Round 1
// baseline (19861.711 us; speedup 1.0000x reference)
//
#include <hip/hip_runtime.h>
#include <math.h>

#define B 128
#define PP 196
#define ENC 2048
#define DEC 512
#define ATTD 512
#define EMB 300
#define VV 10000
#define CAPLEN 51
#define TT 50
#define XDIM 2348   // EMB+ENC
#define KTOT 2860   // XDIM+DEC

static const long long OFF_PRED = 0LL;
static const long long OFF_CAPS = 64000000LL;   // B*TT*VV
static const long long OFF_DECL = 64006528LL;   // + B*CAPLEN
static const long long OFF_ALPH = 64006656LL;   // + B
static const long long OFF_SORT = 65261056LL;   // + B*TT*PP

__device__ __forceinline__ float sigf(float x){ return 1.f/(1.f+expf(-x)); }

// ---------------- sort + caps + decode_lengths + sort_ind ----------------
__global__ __launch_bounds__(128) void k_prep(const int* __restrict__ cap_len,
    const int* __restrict__ enc_caps, float* __restrict__ out,
    int* __restrict__ sort_i, int* __restrict__ decl_i, int* __restrict__ caps_i){
  __shared__ int lens[B];
  __shared__ int sind[B];
  int t = threadIdx.x;
  lens[t] = cap_len[t];
  __syncthreads();
  int my = lens[t];
  int rank = 0;
  for (int j=0;j<B;j++){
    int lj = lens[j];
    if (lj > my || (lj == my && j < t)) rank++;
  }
  sind[rank] = t;           // stable argsort(-lens)
  __syncthreads();
  int src = sind[t];
  sort_i[t] = src;
  int dl = lens[src]-1;
  decl_i[t] = dl;
  out[OFF_DECL+t] = (float)dl;
  out[OFF_SORT+t] = (float)src;
  for (int j=0;j<CAPLEN;j++){
    int v = enc_caps[src*CAPLEN+j];
    caps_i[t*CAPLEN+j] = v;
    out[OFF_CAPS + t*CAPLEN + j] = (float)v;
  }
}

// ---------------- mean over P of sorted encoder_out ----------------
__global__ __launch_bounds__(256) void k_mean(const float* __restrict__ enc,
    const int* __restrict__ sort_i, float* __restrict__ meanb){
  int b = blockIdx.x;
  int e = blockIdx.y*256 + threadIdx.x;
  int sb = sort_i[b];
  const float* p0 = enc + (size_t)sb*PP*ENC + e;
  float s = 0.f;
  for (int p=0;p<PP;p++) s += p0[(size_t)p*ENC];
  meanb[b*ENC+e] = s * (1.0f/PP);
}

// ---------------- h0/c0 : meanb @ W_init.T + b  (tile 128x32, K=2048) ----------------
__global__ __launch_bounds__(256) void k_init(const float* __restrict__ meanb,
    const float* __restrict__ Wh, const float* __restrict__ bh,
    const float* __restrict__ Wc, const float* __restrict__ bc,
    float* __restrict__ h, float* __restrict__ c){
  __shared__ float aT[64*132];
  __shared__ float wT[64*36];
  int tid = threadIdx.x;
  int n0 = blockIdx.x*32;
  const float* Wm  = blockIdx.y ? Wc : Wh;
  const float* bia = blockIdx.y ? bc : bh;
  float* dst = blockIdx.y ? c : h;
  int bt = tid&15, nt = tid>>4;
  float acc[8][2] = {};
  for (int k0=0;k0<ENC;k0+=64){
    for (int idx=tid; idx<64*128; idx+=256){
      int k=idx&63, m=idx>>6;
      aT[k*132+m] = meanb[m*ENC + k0+k];
    }
    for (int idx=tid; idx<64*32; idx+=256){
      int k=idx&63, n=idx>>6;
      wT[k*36+n] = Wm[(size_t)(n0+n)*ENC + k0+k];
    }
    __syncthreads();
    #pragma unroll 4
    for (int k=0;k<64;k++){
      float a[8], w[2];
      *(float4*)&a[0] = *(const float4*)&aT[k*132+bt*8];
      *(float4*)&a[4] = *(const float4*)&aT[k*132+bt*8+4];
      *(float2*)&w[0] = *(const float2*)&wT[k*36+nt*2];
      #pragma unroll
      for (int i=0;i<8;i++){ acc[i][0]+=a[i]*w[0]; acc[i][1]+=a[i]*w[1]; }
    }
    __syncthreads();
  }
  #pragma unroll
  for (int i=0;i<8;i++){
    int m = bt*8+i;
    #pragma unroll
    for (int j=0;j<2;j++){
      int n = n0+nt*2+j;
      dst[m*DEC+n] = acc[i][j] + bia[n];
    }
  }
}

// ---------------- att1 = enc_sorted @ W_enc_att.T + b  (tile 128x64, K=2048) ----------------
__global__ __launch_bounds__(256) void k_att1(const float* __restrict__ enc,
    const float* __restrict__ Wea, const float* __restrict__ bea,
    const int* __restrict__ sort_i, float* __restrict__ att1){
  __shared__ float aT[64*132];
  __shared__ float wT[64*68];
  int tid = threadIdx.x;
  int m0 = blockIdx.x*128;
  int n0 = blockIdx.y*64;
  int bt = tid&15, nt = tid>>4;
  float acc[8][4] = {};
  for (int k0=0;k0<ENC;k0+=64){
    for (int idx=tid; idx<64*128; idx+=256){
      int k=idx&63, m=idx>>6;
      int mg = m0+m;
      int b = mg/196; int p = mg - b*196;
      int sb = sort_i[b];
      aT[k*132+m] = enc[((size_t)sb*PP + p)*ENC + k0+k];
    }
    for (int idx=tid; idx<64*64; idx+=256){
      int k=idx&63, n=idx>>6;
      wT[k*68+n] = Wea[(size_t)(n0+n)*ENC + k0+k];
    }
    __syncthreads();
    #pragma unroll 4
    for (int k=0;k<64;k++){
      float a[8], w[4];
      *(float4*)&a[0] = *(const float4*)&aT[k*132+bt*8];
      *(float4*)&a[4] = *(const float4*)&aT[k*132+bt*8+4];
      *(float4*)&w[0] = *(const float4*)&wT[k*68+nt*4];
      #pragma unroll
      for (int i=0;i<8;i++)
        #pragma unroll
        for (int j=0;j<4;j++) acc[i][j] += a[i]*w[j];
    }
    __syncthreads();
  }
  #pragma unroll
  for (int i=0;i<8;i++){
    int mg = m0+bt*8+i;
    #pragma unroll
    for (int j=0;j<4;j++){
      int n = n0+nt*4+j;
      att1[(size_t)mg*ATTD + n] = acc[i][j] + bea[n];
    }
  }
}

// ---------------- per-step attention: att2 -> score -> softmax -> awe ----------------
__global__ __launch_bounds__(256) void k_attn(const float* __restrict__ enc,
    const float* __restrict__ att1, const float* __restrict__ h,
    const float* __restrict__ Wda, const float* __restrict__ bda,
    const float* __restrict__ wfa, const float* __restrict__ bfa,
    const int* __restrict__ sort_i, const int* __restrict__ decl_i,
    float* __restrict__ awe, float* __restrict__ out, int t){
  __shared__ float s_h[DEC];
  __shared__ float s_a2[ATTD];
  __shared__ float s_w[ATTD];
  __shared__ float s_sc[PP];
  __shared__ float s_red[4];
  int b = blockIdx.x, tid = threadIdx.x;
  size_t aoff = (size_t)OFF_ALPH + ((size_t)b*TT + t)*PP;
  bool active = t < decl_i[b];
  if (!active){
    if (tid < PP) out[aoff+tid] = 0.f;
    return;
  }
  s_h[tid] = h[b*DEC+tid];  s_h[tid+256] = h[b*DEC+tid+256];
  s_w[tid] = wfa[tid];      s_w[tid+256] = wfa[tid+256];
  __syncthreads();
  { // att2 = h @ W_dec_att.T + b  (thread computes j and j+256)
    const float4* h4 = (const float4*)s_h;
    const float4* W4 = (const float4*)Wda;
    float a0=0.f, a1=0.f;
    int j0 = tid, j1 = tid+256;
    #pragma unroll 4
    for (int k=0;k<DEC/4;k++){
      float4 hv = h4[k];
      float4 w0 = W4[(size_t)j0*(DEC/4)+k];
      float4 w1 = W4[(size_t)j1*(DEC/4)+k];
      a0 += hv.x*w0.x+hv.y*w0.y+hv.z*w0.z+hv.w*w0.w;
      a1 += hv.x*w1.x+hv.y*w1.y+hv.z*w1.z+hv.w*w1.w;
    }
    s_a2[j0] = a0 + bda[j0];
    s_a2[j1] = a1 + bda[j1];
  }
  __syncthreads();
  int wid = tid>>6, lane = tid&63;
  float b0 = bfa[0];
  const float4* A14 = (const float4*)(att1 + (size_t)b*PP*ATTD);
  const float4* a24 = (const float4*)s_a2;
  const float4* wf4 = (const float4*)s_w;
  for (int p=wid; p<PP; p+=4){   // wave per p
    const float4* row = A14 + (size_t)p*(ATTD/4);
    int k = lane*2;
    float4 x0=row[k], x1=row[k+1];
    float4 t0=a24[k], t1=a24[k+1];
    float4 v0=wf4[k], v1=wf4[k+1];
    float s = fmaxf(x0.x+t0.x,0.f)*v0.x + fmaxf(x0.y+t0.y,0.f)*v0.y
            + fmaxf(x0.z+t0.z,0.f)*v0.z + fmaxf(x0.w+t0.w,0.f)*v0.w
            + fmaxf(x1.x+t1.x,0.f)*v1.x + fmaxf(x1.y+t1.y,0.f)*v1.y
            + fmaxf(x1.z+t1.z,0.f)*v1.z + fmaxf(x1.w+t1.w,0.f)*v1.w;
    #pragma unroll
    for (int off=32;off;off>>=1) s += __shfl_down(s,off);
    if (lane==0) s_sc[p] = s + b0;
  }
  __syncthreads();
  float sc = (tid<PP) ? s_sc[tid] : -1e30f;
  float mx = sc;
  #pragma unroll
  for (int off=32;off;off>>=1) mx = fmaxf(mx, __shfl_down(mx,off));
  if (lane==0) s_red[wid] = mx;
  __syncthreads();
  mx = fmaxf(fmaxf(s_red[0],s_red[1]), fmaxf(s_red[2],s_red[3]));
  float e = (tid<PP) ? expf(sc-mx) : 0.f;
  float sm = e;
  #pragma unroll
  for (int off=32;off;off>>=1) sm += __shfl_down(sm,off);
  __syncthreads();
  if (lane==0) s_red[wid] = sm;
  __syncthreads();
  float inv = 1.f/(s_red[0]+s_red[1]+s_red[2]+s_red[3]);
  float alpha = e*inv;
  if (tid<PP){ s_sc[tid] = alpha; out[aoff+tid] = alpha; }
  __syncthreads();
  // awe = alpha @ enc[b]
  int sb = sort_i[b];
  const float4* encb = (const float4*)(enc + (size_t)sb*PP*ENC);
  float4 acc0 = {0,0,0,0}, acc1 = {0,0,0,0};
  for (int p=0;p<PP;p++){
    float a = s_sc[p];
    const float4* r = encb + (size_t)p*(ENC/4);
    float4 u = r[tid], v = r[tid+256];
    acc0.x+=a*u.x; acc0.y+=a*u.y; acc0.z+=a*u.z; acc0.w+=a*u.w;
    acc1.x+=a*v.x; acc1.y+=a*v.y; acc1.z+=a*v.z; acc1.w+=a*v.w;
  }
  float4* aw = (float4*)(awe + (size_t)b*ENC);
  aw[tid] = acc0; aw[tid+256] = acc1;
}

// ---------------- gate = sigmoid(h @ W_fbeta.T + b)  (tile 128x32, K=512) ----------------
__global__ __launch_bounds__(256) void k_gate(const float* __restrict__ h,
    const float* __restrict__ Wfb, const float* __restrict__ bfb,
    float* __restrict__ gate){
  __shared__ float aT[64*132];
  __shared__ float wT[64*36];
  int tid = threadIdx.x;
  int n0 = blockIdx.x*32;
  int bt = tid&15, nt = tid>>4;
  float acc[8][2] = {};
  for (int k0=0;k0<DEC;k0+=64){
    for (int idx=tid; idx<64*128; idx+=256){
      int k=idx&63, m=idx>>6;
      aT[k*132+m] = h[m*DEC + k0+k];
    }
    for (int idx=tid; idx<64*32; idx+=256){
      int k=idx&63, n=idx>>6;
      wT[k*36+n] = Wfb[(size_t)(n0+n)*DEC + k0+k];
    }
    __syncthreads();
    #pragma unroll 4
    for (int k=0;k<64;k++){
      float a[8], w[2];
      *(float4*)&a[0] = *(const float4*)&aT[k*132+bt*8];
      *(float4*)&a[4] = *(const float4*)&aT[k*132+bt*8+4];
      *(float2*)&w[0] = *(const float2*)&wT[k*36+nt*2];
      #pragma unroll
      for (int i=0;i<8;i++){ acc[i][0]+=a[i]*w[0]; acc[i][1]+=a[i]*w[1]; }
    }
    __syncthreads();
  }
  #pragma unroll
  for (int i=0;i<8;i++){
    int m = bt*8+i;
    #pragma unroll
    for (int j=0;j<2;j++){
      int n = n0+nt*2+j;
      gate[m*ENC+n] = sigf(acc[i][j] + bfb[n]);
    }
  }
}

// ---------------- gates GEMM (split-K): pbuf[s] = x@W_ih.T + h@W_hh.T partial ----------------
__global__ __launch_bounds__(256) void k_b1(const float* __restrict__ embedding,
    const int* __restrict__ caps_i, const float* __restrict__ gate,
    const float* __restrict__ awe, const float* __restrict__ h,
    const float* __restrict__ W_ih, const float* __restrict__ W_hh,
    float* __restrict__ pbuf, int t){
  __shared__ float aT[64*132];
  __shared__ float wT[64*68];
  int tid = threadIdx.x;
  int n0 = blockIdx.x*64;
  int s  = blockIdx.y;
  int Kbeg = s*358;
  int Kend = min(KTOT, Kbeg+358);
  int bt = tid&15, nt = tid>>4;
  float acc[8][4] = {};
  for (int k0=Kbeg;k0<Kend;k0+=64){
    for (int idx=tid; idx<64*128; idx+=256){
      int k=idx&63, m=idx>>6;
      int kk = k0+k;
      float v = 0.f;
      if (kk < Kend){
        if (kk < EMB){
          int tok = caps_i[m*CAPLEN+t];
          v = embedding[(size_t)tok*EMB + kk];
        } else if (kk < XDIM){
          int e = kk-EMB;
          v = gate[m*ENC+e]*awe[m*ENC+e];
        } else {
          v = h[m*DEC + kk-XDIM];
        }
      }
      aT[k*132+m] = v;
    }
    for (int idx=tid; idx<64*64; idx+=256){
      int k=idx&63, n=idx>>6;
      int kk = k0+k;
      float v = 0.f;
      if (kk < Kend){
        if (kk < XDIM) v = W_ih[(size_t)(n0+n)*XDIM + kk];
        else           v = W_hh[(size_t)(n0+n)*DEC + kk-XDIM];
      }
      wT[k*68+n] = v;
    }
    __syncthreads();
    #pragma unroll 4
    for (int k=0;k<64;k++){
      float a[8], w[4];
      *(float4*)&a[0] = *(const float4*)&aT[k*132+bt*8];
      *(float4*)&a[4] = *(const float4*)&aT[k*132+bt*8+4];
      *(float4*)&w[0] = *(const float4*)&wT[k*68+nt*4];
      #pragma unroll
      for (int i=0;i<8;i++)
        #pragma unroll
        for (int j=0;j<4;j++) acc[i][j] += a[i]*w[j];
    }
    __syncthreads();
  }
  #pragma unroll
  for (int i=0;i<8;i++){
    int m = bt*8+i;
    #pragma unroll
    for (int j=0;j<4;j++){
      int n = n0+nt*4+j;
      pbuf[((size_t)s*B + m)*2048 + n] = acc[i][j];
    }
  }
}

// ---------------- reduce split-K + LSTM cell update ----------------
__global__ __launch_bounds__(256) void k_b2(const float* __restrict__ pbuf,
    const float* __restrict__ b_ih, const float* __restrict__ b_hh,
    const int* __restrict__ decl_i, float* __restrict__ h, float* __restrict__ c,
    float* __restrict__ h_new, int t){
  int b = blockIdx.x;
  int j = blockIdx.y*256 + threadIdx.x;
  float gi = b_ih[j]        + b_hh[j];
  float gf = b_ih[DEC+j]    + b_hh[DEC+j];
  float gg = b_ih[2*DEC+j]  + b_hh[2*DEC+j];
  float go = b_ih[3*DEC+j]  + b_hh[3*DEC+j];
  for (int s=0;s<8;s++){
    const float* p = pbuf + ((size_t)s*B + b)*2048;
    gi += p[j]; gf += p[DEC+j]; gg += p[2*DEC+j]; go += p[3*DEC+j];
  }
  float i_ = sigf(gi), f_ = sigf(gf), g_ = tanhf(gg), o_ = sigf(go);
  float cn = f_*c[b*DEC+j] + i_*g_;
  float hn = o_*tanhf(cn);
  h_new[b*DEC+j] = hn;
  if (t < decl_i[b]){ h[b*DEC+j] = hn; c[b*DEC+j] = cn; }
}

// ---------------- preds = h_new @ W_fc.T + b_fc, masked  (tile 128x32, K=512) ----------------
__global__ __launch_bounds__(256) void k_pred(const float* __restrict__ h_new,
    const float* __restrict__ W_fc, const float* __restrict__ b_fc,
    const int* __restrict__ decl_i, float* __restrict__ out, int t){
  __shared__ float aT[64*132];
  __shared__ float wT[64*36];
  int tid = threadIdx.x;
  int n0 = blockIdx.x*32;
  int bt = tid&15, nt = tid>>4;
  float acc[8][2] = {};
  for (int k0=0;k0<DEC;k0+=64){
    for (int idx=tid; idx<64*128; idx+=256){
      int k=idx&63, m=idx>>6;
      aT[k*132+m] = h_new[m*DEC + k0+k];
    }
    for (int idx=tid; idx<64*32; idx+=256){
      int k=idx&63, n=idx>>6;
      int ng = n0+n;
      wT[k*36+n] = (ng<VV) ? W_fc[(size_t)ng*DEC + k0+k] : 0.f;
    }
    __syncthreads();
    #pragma unroll 4
    for (int k=0;k<64;k++){
      float a[8], w[2];
      *(float4*)&a[0] = *(const float4*)&aT[k*132+bt*8];
      *(float4*)&a[4] = *(const float4*)&aT[k*132+bt*8+4];
      *(float2*)&w[0] = *(const float2*)&wT[k*36+nt*2];
      #pragma unroll
      for (int i=0;i<8;i++){ acc[i][0]+=a[i]*w[0]; acc[i][1]+=a[i]*w[1]; }
    }
    __syncthreads();
  }
  #pragma unroll
  for (int i=0;i<8;i++){
    int m = bt*8+i;
    bool act = t < decl_i[m];
    #pragma unroll
    for (int j=0;j<2;j++){
      int n = n0+nt*2+j;
      if (n < VV)
        out[OFF_PRED + ((size_t)m*TT + t)*VV + n] = act ? (acc[i][j]+b_fc[n]) : 0.f;
    }
  }
}

extern "C" void kernel_launch(void* const* d_in, const int* in_sizes, int n_in,
                              void* d_out, int out_size, void* d_ws, size_t ws_size,
                              hipStream_t stream){
  const float* enc       = (const float*)d_in[0];
  const int*   caps_in   = (const int*)d_in[1];
  const int*   caplen    = (const int*)d_in[2];
  const float* W_enc_att = (const float*)d_in[3];
  const float* b_enc_att = (const float*)d_in[4];
  const float* W_dec_att = (const float*)d_in[5];
  const float* b_dec_att = (const float*)d_in[6];
  const float* w_full_att= (const float*)d_in[7];
  const float* b_full_att= (const float*)d_in[8];
  const float* embedding = (const float*)d_in[9];
  const float* W_ih      = (const float*)d_in[10];
  const float* b_ih      = (const float*)d_in[11];
  const float* W_hh      = (const float*)d_in[12];
  const float* b_hh      = (const float*)d_in[13];
  const float* W_init_h  = (const float*)d_in[14];
  const float* b_init_h  = (const float*)d_in[15];
  const float* W_init_c  = (const float*)d_in[16];
  const float* b_init_c  = (const float*)d_in[17];
  const float* W_fbeta   = (const float*)d_in[18];
  const float* b_fbeta   = (const float*)d_in[19];
  const float* W_fc      = (const float*)d_in[20];
  const float* b_fc      = (const float*)d_in[21];
  float* out = (float*)d_out;

  float* W     = (float*)d_ws;
  float* h     = W;                    // 128*512
  float* c     = W + 65536;            // 128*512
  float* h_new = W + 131072;           // 128*512
  float* meanb = W + 196608;           // 128*2048
  float* awe   = W + 458752;           // 128*2048
  float* gate  = W + 720896;           // 128*2048
  float* pbuf  = W + 983040;           // 8*128*2048
  float* att1  = W + 3080192;          // 128*196*512
  int*   ipart = (int*)(W + 15925248);
  int* sort_i = ipart;
  int* decl_i = ipart + 128;
  int* caps_i = ipart + 256;           // 128*51

  k_prep<<<1,128,0,stream>>>(caplen, caps_in, out, sort_i, decl_i, caps_i);
  k_mean<<<dim3(128,8),256,0,stream>>>(enc, sort_i, meanb);
  k_init<<<dim3(16,2),256,0,stream>>>(meanb, W_init_h, b_init_h, W_init_c, b_init_c, h, c);
  k_att1<<<dim3(196,8),256,0,stream>>>(enc, W_enc_att, b_enc_att, sort_i, att1);

  for (int t=0;t<TT;t++){
    k_attn<<<128,256,0,stream>>>(enc, att1, h, W_dec_att, b_dec_att,
                                 w_full_att, b_full_att, sort_i, decl_i, awe, out, t);
    k_gate<<<64,256,0,stream>>>(h, W_fbeta, b_fbeta, gate);
    k_b1<<<dim3(32,8),256,0,stream>>>(embedding, caps_i, gate, awe, h,
                                      W_ih, W_hh, pbuf, t);
    k_b2<<<dim3(128,2),256,0,stream>>>(pbuf, b_ih, b_hh, decl_i, h, c, h_new, t);
    k_pred<<<313,256,0,stream>>>(h_new, W_fc, b_fc, decl_i, out, t);
  }
}

// Round 2
// 13451.059 us; speedup vs baseline: 1.4766x; 1.4766x over previous
//
#include <hip/hip_runtime.h>
#include <math.h>

#define B 128
#define PP 196
#define ENC 2048
#define DEC 512
#define ATTD 512
#define EMB 300
#define VV 10000
#define CAPLEN 51
#define TT 50
#define XDIM 2348   // EMB+ENC
#define KTOT 2860   // XDIM+DEC

static const long long OFF_PRED = 0LL;
static const long long OFF_CAPS = 64000000LL;   // B*TT*VV
static const long long OFF_DECL = 64006528LL;   // + B*CAPLEN
static const long long OFF_ALPH = 64006656LL;   // + B
static const long long OFF_SORT = 65261056LL;   // + B*TT*PP

typedef unsigned short ushort_t;
typedef unsigned int uint_t;

__device__ __forceinline__ float sigf(float x){ return 1.f/(1.f+expf(-x)); }

__device__ __forceinline__ float b2f(ushort_t u){
  union{uint_t i; float f;} v; v.i = ((uint_t)u)<<16; return v.f;
}
__device__ __forceinline__ ushort_t f2b(float f){
  union{float f; uint_t i;} v; v.f = f;
  uint_t r = v.i + 0x7fffu + ((v.i>>16)&1u);
  return (ushort_t)(r>>16);
}
__device__ __forceinline__ uint_t pack2(float lo, float hi){
  return (uint_t)f2b(lo) | ((uint_t)f2b(hi)<<16);
}
__device__ __forceinline__ float2 b2x2(uint_t u){
  union{uint_t i; float f;} a,b; a.i = u<<16; b.i = u & 0xffff0000u;
  return make_float2(a.f, b.f);  // (low elem, high elem)
}

// ---------------- sort + caps + decode_lengths + sort_ind ----------------
__global__ __launch_bounds__(128) void k_prep(const int* __restrict__ cap_len,
    const int* __restrict__ enc_caps, float* __restrict__ out,
    int* __restrict__ sort_i, int* __restrict__ decl_i, int* __restrict__ caps_i){
  __shared__ int lens[B];
  __shared__ int sind[B];
  int t = threadIdx.x;
  lens[t] = cap_len[t];
  __syncthreads();
  int my = lens[t];
  int rank = 0;
  for (int j=0;j<B;j++){
    int lj = lens[j];
    if (lj > my || (lj == my && j < t)) rank++;
  }
  sind[rank] = t;
  __syncthreads();
  int src = sind[t];
  sort_i[t] = src;
  int dl = lens[src]-1;
  decl_i[t] = dl;
  out[OFF_DECL+t] = (float)dl;
  out[OFF_SORT+t] = (float)src;
  for (int j=0;j<CAPLEN;j++){
    int v = enc_caps[src*CAPLEN+j];
    caps_i[t*CAPLEN+j] = v;
    out[OFF_CAPS + t*CAPLEN + j] = (float)v;
  }
}

// ---------------- mean over P of sorted encoder_out ----------------
__global__ __launch_bounds__(256) void k_mean(const float* __restrict__ enc,
    const int* __restrict__ sort_i, float* __restrict__ meanb){
  int b = blockIdx.x;
  int e = blockIdx.y*256 + threadIdx.x;
  int sb = sort_i[b];
  const float* p0 = enc + (size_t)sb*PP*ENC + e;
  float s = 0.f;
  for (int p=0;p<PP;p++) s += p0[(size_t)p*ENC];
  meanb[b*ENC+e] = s * (1.0f/PP);
}

// ---------------- h0/c0 : meanb @ W_init.T + b ----------------
__global__ __launch_bounds__(256) void k_init(const float* __restrict__ meanb,
    const float* __restrict__ Wh, const float* __restrict__ bh,
    const float* __restrict__ Wc, const float* __restrict__ bc,
    float* __restrict__ h, float* __restrict__ c){
  __shared__ float aT[64*132];
  __shared__ float wT[64*36];
  int tid = threadIdx.x;
  int n0 = blockIdx.x*32;
  const float* Wm  = blockIdx.y ? Wc : Wh;
  const float* bia = blockIdx.y ? bc : bh;
  float* dst = blockIdx.y ? c : h;
  int bt = tid&15, nt = tid>>4;
  float acc[8][2] = {};
  for (int k0=0;k0<ENC;k0+=64){
    for (int idx=tid; idx<64*128; idx+=256){
      int k=idx&63, m=idx>>6;
      aT[k*132+m] = meanb[m*ENC + k0+k];
    }
    for (int idx=tid; idx<64*32; idx+=256){
      int k=idx&63, n=idx>>6;
      wT[k*36+n] = Wm[(size_t)(n0+n)*ENC + k0+k];
    }
    __syncthreads();
    #pragma unroll 4
    for (int k=0;k<64;k++){
      float a[8], w[2];
      *(float4*)&a[0] = *(const float4*)&aT[k*132+bt*8];
      *(float4*)&a[4] = *(const float4*)&aT[k*132+bt*8+4];
      *(float2*)&w[0] = *(const float2*)&wT[k*36+nt*2];
      #pragma unroll
      for (int i=0;i<8;i++){ acc[i][0]+=a[i]*w[0]; acc[i][1]+=a[i]*w[1]; }
    }
    __syncthreads();
  }
  #pragma unroll
  for (int i=0;i<8;i++){
    int m = bt*8+i;
    #pragma unroll
    for (int j=0;j<2;j++){
      int n = n0+nt*2+j;
      dst[m*DEC+n] = acc[i][j] + bia[n];
    }
  }
}

// ---------------- f32 -> bf16 streaming convert (8 elems/thread) ----------------
__global__ __launch_bounds__(256) void k_cvt(const float* __restrict__ src,
    ushort_t* __restrict__ dst, int n8){
  int i = blockIdx.x*256 + threadIdx.x;
  if (i >= n8) return;
  const float4* s4 = (const float4*)src + (size_t)i*2;
  float4 f0 = s4[0], f1 = s4[1];
  uint4 q;
  q.x = pack2(f0.x,f0.y); q.y = pack2(f0.z,f0.w);
  q.z = pack2(f1.x,f1.y); q.w = pack2(f1.z,f1.w);
  ((uint4*)dst)[i] = q;
}

// ---------------- sorted enc -> bf16 ----------------
__global__ __launch_bounds__(256) void k_encb(const float* __restrict__ enc,
    const int* __restrict__ sort_i, ushort_t* __restrict__ encb){
  int row = blockIdx.x;               // 0..25087
  int b = row/PP, p = row - b*PP;
  int sb = sort_i[b];
  const float4* s4 = (const float4*)(enc + ((size_t)sb*PP+p)*ENC);
  uint4* d4 = (uint4*)(encb + (size_t)row*ENC);
  int tid = threadIdx.x;
  float4 f0 = s4[tid*2], f1 = s4[tid*2+1];
  uint4 q;
  q.x = pack2(f0.x,f0.y); q.y = pack2(f0.z,f0.w);
  q.z = pack2(f1.x,f1.y); q.w = pack2(f1.z,f1.w);
  d4[tid] = q;
}

// ---------------- transpose W_fbeta -> [DEC][ENC] ----------------
__global__ __launch_bounds__(256) void k_wfbT(const float* __restrict__ Wfb,
    float* __restrict__ wfbT){
  int k = blockIdx.x;
  for (int ch=threadIdx.x; ch<ENC; ch+=256)
    wfbT[(size_t)k*ENC+ch] = Wfb[(size_t)ch*DEC+k];
}

// ---------------- prestage embeddings for all (b,t) ----------------
__global__ __launch_bounds__(320) void k_embpre(const float* __restrict__ embedding,
    const int* __restrict__ caps_i, float* __restrict__ embp){
  int b = blockIdx.x, t = blockIdx.y, tid = threadIdx.x;
  if (tid >= EMB) return;
  int tok = caps_i[b*CAPLEN+t];
  embp[((size_t)b*TT+t)*EMB + tid] = embedding[(size_t)tok*EMB + tid];
}

// ---------------- att1 = enc_sorted @ W_enc_att.T + b  -> bf16 ----------------
__global__ __launch_bounds__(256) void k_att1(const float* __restrict__ enc,
    const float* __restrict__ Wea, const float* __restrict__ bea,
    const int* __restrict__ sort_i, ushort_t* __restrict__ attb){
  __shared__ float aT[64*132];
  __shared__ float wT[64*68];
  int tid = threadIdx.x;
  int m0 = blockIdx.x*128;
  int n0 = blockIdx.y*64;
  int bt = tid&15, nt = tid>>4;
  float acc[8][4] = {};
  for (int k0=0;k0<ENC;k0+=64){
    for (int idx=tid; idx<64*128; idx+=256){
      int k=idx&63, m=idx>>6;
      int mg = m0+m;
      int b = mg/PP; int p = mg - b*PP;
      int sb = sort_i[b];
      aT[k*132+m] = enc[((size_t)sb*PP + p)*ENC + k0+k];
    }
    for (int idx=tid; idx<64*64; idx+=256){
      int k=idx&63, n=idx>>6;
      wT[k*68+n] = Wea[(size_t)(n0+n)*ENC + k0+k];
    }
    __syncthreads();
    #pragma unroll 4
    for (int k=0;k<64;k++){
      float a[8], w[4];
      *(float4*)&a[0] = *(const float4*)&aT[k*132+bt*8];
      *(float4*)&a[4] = *(const float4*)&aT[k*132+bt*8+4];
      *(float4*)&w[0] = *(const float4*)&wT[k*68+nt*4];
      #pragma unroll
      for (int i=0;i<8;i++)
        #pragma unroll
        for (int j=0;j<4;j++) acc[i][j] += a[i]*w[j];
    }
    __syncthreads();
  }
  #pragma unroll
  for (int i=0;i<8;i++){
    int mg = m0+bt*8+i;
    #pragma unroll
    for (int j=0;j<4;j++){
      int n = n0+nt*4+j;
      attb[(size_t)mg*ATTD + n] = f2b(acc[i][j] + bea[n]);
    }
  }
}

// ---------------- one-time masked-zero writes for preds + alphas ----------------
__global__ __launch_bounds__(256) void k_zero(const int* __restrict__ decl_i,
    float* __restrict__ out){
  int blk = blockIdx.x;                 // 0..6399
  int b = blk/TT, t = blk - b*TT;
  if (t < decl_i[b]) return;
  float4 z = {0.f,0.f,0.f,0.f};
  float4* p = (float4*)(out + OFF_PRED + ((size_t)b*TT+t)*VV);
  for (int i=threadIdx.x; i<VV/4; i+=256) p[i] = z;
  size_t ao = (size_t)OFF_ALPH + ((size_t)b*TT+t)*PP;
  if (threadIdx.x < PP) out[ao + threadIdx.x] = 0.f;
}

// ---------------- per-step: att2 -> score -> softmax -> awe ----------------
template<bool ENCB>
__global__ __launch_bounds__(512) void k_score_awe(
    const float* __restrict__ enc, const ushort_t* __restrict__ encb,
    const ushort_t* __restrict__ attb, const float* __restrict__ h,
    const float* __restrict__ Wda, const float* __restrict__ bda,
    const float* __restrict__ wfa, const float* __restrict__ bfa,
    const int* __restrict__ sort_i, const int* __restrict__ decl_i,
    float* __restrict__ awe, float* __restrict__ out, int t){
  int b = blockIdx.x, tid = threadIdx.x;
  if (t >= decl_i[b]) return;
  __shared__ float s_h[DEC], s_a2[ATTD], s_w[ATTD];
  __shared__ float s_sc[200], s_al[200];
  __shared__ float s_red[8], s_red2[8];
  s_h[tid] = h[b*DEC+tid];
  s_w[tid] = wfa[tid];
  __syncthreads();
  // att2 = h @ W_dec_att.T + b : one output per thread, row-streamed
  {
    const float4* h4 = (const float4*)s_h;
    const float4* W4 = (const float4*)(Wda + (size_t)tid*DEC);
    float a = 0.f;
    #pragma unroll 8
    for (int k=0;k<DEC/4;k++){
      float4 hv = h4[k]; float4 w = W4[k];
      a += hv.x*w.x + hv.y*w.y + hv.z*w.z + hv.w*w.w;
    }
    s_a2[tid] = a + bda[tid];
  }
  __syncthreads();
  int wid = tid>>6, lane = tid&63;
  float b0 = bfa[0];
  // scores: wave per p
  for (int p=wid; p<PP; p+=8){
    uint4 q = ((const uint4*)(attb + ((size_t)b*PP + p)*ATTD))[lane];
    int j = lane*8;
    float2 x0=b2x2(q.x), x1=b2x2(q.y), x2=b2x2(q.z), x3=b2x2(q.w);
    float s = fmaxf(x0.x+s_a2[j+0],0.f)*s_w[j+0] + fmaxf(x0.y+s_a2[j+1],0.f)*s_w[j+1]
            + fmaxf(x1.x+s_a2[j+2],0.f)*s_w[j+2] + fmaxf(x1.y+s_a2[j+3],0.f)*s_w[j+3]
            + fmaxf(x2.x+s_a2[j+4],0.f)*s_w[j+4] + fmaxf(x2.y+s_a2[j+5],0.f)*s_w[j+5]
            + fmaxf(x3.x+s_a2[j+6],0.f)*s_w[j+6] + fmaxf(x3.y+s_a2[j+7],0.f)*s_w[j+7];
    #pragma unroll
    for (int off=32;off;off>>=1) s += __shfl_down(s,off);
    if (lane==0) s_sc[p] = s + b0;
  }
  __syncthreads();
  // softmax over 196
  float sc = (tid<PP) ? s_sc[tid] : -1e30f;
  float mx = sc;
  #pragma unroll
  for (int off=32;off;off>>=1) mx = fmaxf(mx, __shfl_down(mx,off));
  if (lane==0) s_red[wid] = mx;
  __syncthreads();
  mx = s_red[0];
  #pragma unroll
  for (int i=1;i<8;i++) mx = fmaxf(mx, s_red[i]);
  float e = (tid<PP) ? expf(sc-mx) : 0.f;
  float sm = e;
  #pragma unroll
  for (int off=32;off;off>>=1) sm += __shfl_down(sm,off);
  if (lane==0) s_red2[wid] = sm;
  __syncthreads();
  float tot = 0.f;
  #pragma unroll
  for (int i=0;i<8;i++) tot += s_red2[i];
  float inv = 1.f/tot;
  if (tid<PP){
    float al = e*inv;
    s_al[tid] = al;
    out[(size_t)OFF_ALPH + ((size_t)b*TT+t)*PP + tid] = al;
  }
  __syncthreads();
  // awe[b][tid*4 .. +4) = sum_p alpha_p * enc[b][p][ch]
  float a0=0.f,a1=0.f,a2=0.f,a3=0.f;
  if (ENCB){
    const uint2* E = (const uint2*)(encb + (size_t)b*PP*ENC) + tid;
    #pragma unroll 4
    for (int p=0;p<PP;p++){
      float al = s_al[p];
      uint2 q = E[(size_t)p*(ENC/4)];
      float2 u = b2x2(q.x), v = b2x2(q.y);
      a0 += al*u.x; a1 += al*u.y; a2 += al*v.x; a3 += al*v.y;
    }
  } else {
    int sb = sort_i[b];
    const float4* E = (const float4*)(enc + (size_t)sb*PP*ENC) + tid;
    #pragma unroll 4
    for (int p=0;p<PP;p++){
      float al = s_al[p];
      float4 q = E[(size_t)p*(ENC/4)];
      a0 += al*q.x; a1 += al*q.y; a2 += al*q.z; a3 += al*q.w;
    }
  }
  float4 r = {a0,a1,a2,a3};
  ((float4*)(awe + (size_t)b*ENC))[tid] = r;
}

// ---------------- per-step: gawe = sigmoid(h @ Wfb.T + b) * awe ----------------
__global__ __launch_bounds__(256) void k_gawe(const float* __restrict__ h,
    const float* __restrict__ wfbT, const float* __restrict__ bfb,
    const float* __restrict__ awe, const int* __restrict__ decl_i,
    float* __restrict__ gawe, int t){
  int b = blockIdx.x, sub = blockIdx.y, tid = threadIdx.x;
  if (t >= decl_i[b]) return;
  __shared__ float s_h[DEC];
  s_h[tid] = h[b*DEC+tid]; s_h[tid+256] = h[b*DEC+256+tid];
  __syncthreads();
  int ch = sub*256 + tid;
  float acc = bfb[ch];
  const float* Wp = wfbT + ch;
  #pragma unroll 8
  for (int k=0;k<DEC;k++) acc += s_h[k]*Wp[(size_t)k*ENC];
  gawe[b*ENC+ch] = sigf(acc)*awe[b*ENC+ch];
}

// ---------------- gates GEMM (split-K), bf16 weights ----------------
template<bool EP>
__global__ __launch_bounds__(256) void k_b1(const float* __restrict__ embp,
    const float* __restrict__ embedding, const int* __restrict__ caps_i,
    const float* __restrict__ gawe, const float* __restrict__ h,
    const ushort_t* __restrict__ wihb, const ushort_t* __restrict__ whhb,
    float* __restrict__ pbuf, int t, int kper){
  __shared__ float aT[64*132];
  __shared__ float wT[64*68];
  int tid = threadIdx.x;
  int n0 = blockIdx.x*64;
  int s  = blockIdx.y;
  int Kbeg = s*kper;
  int Kend = min(KTOT, Kbeg+kper);
  int bt = tid&15, nt = tid>>4;
  float acc[8][4] = {};
  for (int k0=Kbeg;k0<Kend;k0+=64){
    for (int idx=tid; idx<64*128; idx+=256){
      int k=idx&63, m=idx>>6;
      int kk = k0+k;
      float v = 0.f;
      if (kk < Kend){
        if (kk < EMB){
          if (EP) v = embp[((size_t)m*TT+t)*EMB + kk];
          else    v = embedding[(size_t)caps_i[m*CAPLEN+t]*EMB + kk];
        } else if (kk < XDIM){
          v = gawe[m*ENC + kk-EMB];
        } else {
          v = h[m*DEC + kk-XDIM];
        }
      }
      aT[k*132+m] = v;
    }
    for (int idx=tid; idx<64*64; idx+=256){
      int k=idx&63, n=idx>>6;
      int kk = k0+k;
      float v = 0.f;
      if (kk < Kend){
        if (kk < XDIM) v = b2f(wihb[(size_t)(n0+n)*XDIM + kk]);
        else           v = b2f(whhb[(size_t)(n0+n)*DEC + kk-XDIM]);
      }
      wT[k*68+n] = v;
    }
    __syncthreads();
    #pragma unroll 4
    for (int k=0;k<64;k++){
      float a[8], w[4];
      *(float4*)&a[0] = *(const float4*)&aT[k*132+bt*8];
      *(float4*)&a[4] = *(const float4*)&aT[k*132+bt*8+4];
      *(float4*)&w[0] = *(const float4*)&wT[k*68+nt*4];
      #pragma unroll
      for (int i=0;i<8;i++)
        #pragma unroll
        for (int j=0;j<4;j++) acc[i][j] += a[i]*w[j];
    }
    __syncthreads();
  }
  #pragma unroll
  for (int i=0;i<8;i++){
    int m = bt*8+i;
    #pragma unroll
    for (int j=0;j<4;j++){
      int n = n0+nt*4+j;
      pbuf[((size_t)s*B + m)*2048 + n] = acc[i][j];
    }
  }
}

// ---------------- reduce split-K + LSTM cell ----------------
__global__ __launch_bounds__(256) void k_b2(const float* __restrict__ pbuf,
    const float* __restrict__ b_ih, const float* __restrict__ b_hh,
    const int* __restrict__ decl_i, float* __restrict__ h, float* __restrict__ c,
    ushort_t* __restrict__ hnb, int t, int nsplit){
  int b = blockIdx.x;
  int j = blockIdx.y*256 + threadIdx.x;
  float gi = b_ih[j]       + b_hh[j];
  float gf = b_ih[DEC+j]   + b_hh[DEC+j];
  float gg = b_ih[2*DEC+j] + b_hh[2*DEC+j];
  float go = b_ih[3*DEC+j] + b_hh[3*DEC+j];
  for (int s=0;s<nsplit;s++){
    const float* p = pbuf + ((size_t)s*B + b)*2048;
    gi += p[j]; gf += p[DEC+j]; gg += p[2*DEC+j]; go += p[3*DEC+j];
  }
  float i_ = sigf(gi), f_ = sigf(gf), g_ = tanhf(gg), o_ = sigf(go);
  float cn = f_*c[b*DEC+j] + i_*g_;
  float hn = o_*tanhf(cn);
  hnb[b*DEC+j] = f2b(hn);
  if (t < decl_i[b]){ h[b*DEC+j] = hn; c[b*DEC+j] = cn; }
}

// ---------------- preds (active rows only), bf16 inputs, 32x64 tiles ----------------
template<bool WB>
__global__ __launch_bounds__(256) void k_pred(const ushort_t* __restrict__ hnb,
    const ushort_t* __restrict__ wfcb, const float* __restrict__ W_fc,
    const float* __restrict__ b_fc, const int* __restrict__ decl_i,
    float* __restrict__ out, int t){
  int m0 = blockIdx.y*32;
  if (decl_i[m0] <= t) return;          // sorted desc -> whole tile inactive
  __shared__ float aT[64*36];
  __shared__ float wT[64*68];
  int tid = threadIdx.x;
  int n0 = blockIdx.x*64;
  int mt = tid&15, nt = tid>>4;
  float acc[2][4] = {};
  for (int k0=0;k0<DEC;k0+=64){
    for (int idx=tid; idx<64*32; idx+=256){
      int k=idx&63, m=idx>>6;
      aT[k*36+m] = b2f(hnb[(m0+m)*DEC + k0+k]);
    }
    for (int idx=tid; idx<64*64; idx+=256){
      int k=idx&63, n=idx>>6;
      int ng = n0+n;
      float v = 0.f;
      if (ng < VV){
        if (WB) v = b2f(wfcb[(size_t)ng*DEC + k0+k]);
        else    v = W_fc[(size_t)ng*DEC + k0+k];
      }
      wT[k*68+n] = v;
    }
    __syncthreads();
    #pragma unroll 4
    for (int k=0;k<64;k++){
      float2 a = *(const float2*)&aT[k*36+mt*2];
      float4 w = *(const float4*)&wT[k*68+nt*4];
      acc[0][0]+=a.x*w.x; acc[0][1]+=a.x*w.y; acc[0][2]+=a.x*w.z; acc[0][3]+=a.x*w.w;
      acc[1][0]+=a.y*w.x; acc[1][1]+=a.y*w.y; acc[1][2]+=a.y*w.z; acc[1][3]+=a.y*w.w;
    }
    __syncthreads();
  }
  #pragma unroll
  for (int i=0;i<2;i++){
    int m = m0 + mt*2 + i;
    if (decl_i[m] <= t) continue;
    #pragma unroll
    for (int j=0;j<4;j++){
      int n = n0 + nt*4 + j;
      if (n < VV)
        out[OFF_PRED + ((size_t)m*TT + t)*VV + n] = acc[i][j] + b_fc[n];
    }
  }
}

extern "C" void kernel_launch(void* const* d_in, const int* in_sizes, int n_in,
                              void* d_out, int out_size, void* d_ws, size_t ws_size,
                              hipStream_t stream){
  const float* enc       = (const float*)d_in[0];
  const int*   caps_in   = (const int*)d_in[1];
  const int*   caplen    = (const int*)d_in[2];
  const float* W_enc_att = (const float*)d_in[3];
  const float* b_enc_att = (const float*)d_in[4];
  const float* W_dec_att = (const float*)d_in[5];
  const float* b_dec_att = (const float*)d_in[6];
  const float* w_full_att= (const float*)d_in[7];
  const float* b_full_att= (const float*)d_in[8];
  const float* embedding = (const float*)d_in[9];
  const float* W_ih      = (const float*)d_in[10];
  const float* b_ih      = (const float*)d_in[11];
  const float* W_hh      = (const float*)d_in[12];
  const float* b_hh      = (const float*)d_in[13];
  const float* W_init_h  = (const float*)d_in[14];
  const float* b_init_h  = (const float*)d_in[15];
  const float* W_init_c  = (const float*)d_in[16];
  const float* b_init_c  = (const float*)d_in[17];
  const float* W_fbeta   = (const float*)d_in[18];
  const float* b_fbeta   = (const float*)d_in[19];
  const float* W_fc      = (const float*)d_in[20];
  const float* b_fc      = (const float*)d_in[21];
  float* out = (float*)d_out;

  float* W = (float*)d_ws;
  size_t o = 0;
  auto A = [&](size_t n){ float* p = W + o; o += n; return p; };

  bool FULL = ws_size >= 182000000ull;   // full plan needs ~181.9 MB
  int SPLIT = FULL ? 15 : 8;
  int kper  = FULL ? 192 : 384;

  float* h     = A(65536);
  float* c     = A(65536);
  float* awe   = A(262144);
  float* gawe  = A(262144);
  float* meanb = A(262144);
  float* pbuf  = A((size_t)SPLIT*262144);
  float* embp  = FULL ? A(1920000) : nullptr;
  float* wfbT  = A(1048576);
  ushort_t* attb = (ushort_t*)A(6422528);
  ushort_t* wihb = (ushort_t*)A(2404352);
  ushort_t* whhb = (ushort_t*)A(524288);
  ushort_t* wfcb = FULL ? (ushort_t*)A(2560000) : nullptr;
  ushort_t* hnb  = (ushort_t*)A(32768);
  ushort_t* encb = FULL ? (ushort_t*)A(25690112) : nullptr;
  int* ip = (int*)A(8192);
  int* sort_i = ip;
  int* decl_i = ip + 128;
  int* caps_i = ip + 256;

  k_prep<<<1,128,0,stream>>>(caplen, caps_in, out, sort_i, decl_i, caps_i);
  k_mean<<<dim3(128,8),256,0,stream>>>(enc, sort_i, meanb);
  k_init<<<dim3(16,2),256,0,stream>>>(meanb, W_init_h, b_init_h, W_init_c, b_init_c, h, c);
  k_cvt<<<(601088+255)/256,256,0,stream>>>(W_ih, wihb, 601088);
  k_cvt<<<(131072+255)/256,256,0,stream>>>(W_hh, whhb, 131072);
  if (FULL) k_cvt<<<(640000+255)/256,256,0,stream>>>(W_fc, wfcb, 640000);
  k_wfbT<<<512,256,0,stream>>>(W_fbeta, wfbT);
  if (FULL) k_embpre<<<dim3(128,50),320,0,stream>>>(embedding, caps_i, embp);
  if (FULL) k_encb<<<25088,256,0,stream>>>(enc, sort_i, encb);
  k_att1<<<dim3(196,8),256,0,stream>>>(enc, W_enc_att, b_enc_att, sort_i, attb);
  k_zero<<<6400,256,0,stream>>>(decl_i, out);

  for (int t=0;t<TT;t++){
    if (FULL)
      k_score_awe<true><<<128,512,0,stream>>>(enc, encb, attb, h, W_dec_att, b_dec_att,
          w_full_att, b_full_att, sort_i, decl_i, awe, out, t);
    else
      k_score_awe<false><<<128,512,0,stream>>>(enc, encb, attb, h, W_dec_att, b_dec_att,
          w_full_att, b_full_att, sort_i, decl_i, awe, out, t);
    k_gawe<<<dim3(128,8),256,0,stream>>>(h, wfbT, b_fbeta, awe, decl_i, gawe, t);
    if (FULL)
      k_b1<true><<<dim3(32,SPLIT),256,0,stream>>>(embp, embedding, caps_i, gawe, h,
          wihb, whhb, pbuf, t, kper);
    else
      k_b1<false><<<dim3(32,SPLIT),256,0,stream>>>(embp, embedding, caps_i, gawe, h,
          wihb, whhb, pbuf, t, kper);
    k_b2<<<dim3(128,2),256,0,stream>>>(pbuf, b_ih, b_hh, decl_i, h, c, hnb, t, SPLIT);
    if (FULL)
      k_pred<true><<<dim3(157,4),256,0,stream>>>(hnb, wfcb, W_fc, b_fc, decl_i, out, t);
    else
      k_pred<false><<<dim3(157,4),256,0,stream>>>(hnb, wfcb, W_fc, b_fc, decl_i, out, t);
  }
}

// Round 3
// 4723.549 us; speedup vs baseline: 4.2048x; 2.8477x over previous
//
#include <hip/hip_runtime.h>
#include <math.h>

#define B 128
#define PP 196
#define ENC 2048
#define DEC 512
#define ATTD 512
#define EMB 300
#define VV 10000
#define CAPLEN 51
#define TT 50
#define KPAD 2880          // 512(h) + 300(emb) + 2048(gawe) + 20 pad
#define NPPAD 10112        // pred N padded to 158*64

static const long long OFF_PRED = 0LL;
static const long long OFF_CAPS = 64000000LL;
static const long long OFF_DECL = 64006528LL;
static const long long OFF_ALPH = 64006656LL;
static const long long OFF_SORT = 65261056LL;

typedef unsigned short ushort_t;
typedef unsigned int uint_t;
typedef short bf8 __attribute__((ext_vector_type(8)));
typedef float f4 __attribute__((ext_vector_type(4)));

__device__ __forceinline__ float sigf(float x){ return 1.f/(1.f+expf(-x)); }
__device__ __forceinline__ float b2f(ushort_t u){
  union{uint_t i; float f;} v; v.i = ((uint_t)u)<<16; return v.f;
}
__device__ __forceinline__ ushort_t f2b(float f){
  union{float f; uint_t i;} v; v.f = f;
  uint_t r = v.i + 0x7fffu + ((v.i>>16)&1u);
  return (ushort_t)(r>>16);
}
__device__ __forceinline__ uint_t pack2(float lo, float hi){
  return (uint_t)f2b(lo) | ((uint_t)f2b(hi)<<16);
}
__device__ __forceinline__ float2 b2x2(uint_t u){
  union{uint_t i; float f;} a,b; a.i = u<<16; b.i = u & 0xffff0000u;
  return make_float2(a.f, b.f);
}

// ======== shared 128x64 MFMA tile body (A[M][K], B(N,K) row-major, bf16) ========
// waves 2x2: wave (wm,wn) owns rows wm*64.., cols wn*32..; frags 4x2 of 16x16, BK=32
__device__ __forceinline__ void gemm128x64(
    const ushort_t* __restrict__ Ab, int lda, int m0,
    const ushort_t* __restrict__ Bb, int ldb, int n0,
    int Kbeg, int Kend, int mbound,
    ushort_t* As, ushort_t* Bs, int tid, f4 acc[4][2])
{
  const int r = tid>>2, cby = (tid&3)*8;
  const int w = tid>>6, l = tid&63;
  const int wm = w>>1, wn = w&1, lr = l&15, lk = (l>>4)*8;
  for (int k0=Kbeg; k0<Kend; k0+=32){
    uint4 qa0 = *(const uint4*)(Ab + (size_t)(m0+r)*lda    + k0 + cby);
    uint4 qa1 = *(const uint4*)(Ab + (size_t)(m0+64+r)*lda + k0 + cby);
    uint4 qb  = *(const uint4*)(Bb + (size_t)(n0+r)*ldb    + k0 + cby);
    __syncthreads();
    *(uint4*)(As + r*40      + cby) = qa0;
    *(uint4*)(As + (64+r)*40 + cby) = qa1;
    *(uint4*)(Bs + r*40      + cby) = qb;
    __syncthreads();
    bf8 b0 = *(const bf8*)(Bs + (wn*32+lr)*40    + lk);
    bf8 b1 = *(const bf8*)(Bs + (wn*32+16+lr)*40 + lk);
    #pragma unroll
    for (int fm=0; fm<4; fm++){
      if (wm*64 + fm*16 >= mbound) break;
      bf8 a = *(const bf8*)(As + (wm*64+fm*16+lr)*40 + lk);
      acc[fm][0] = __builtin_amdgcn_mfma_f32_16x16x32_bf16(a, b0, acc[fm][0], 0, 0, 0);
      acc[fm][1] = __builtin_amdgcn_mfma_f32_16x16x32_bf16(a, b1, acc[fm][1], 0, 0, 0);
    }
  }
}

// ---------------- sort + caps + decode_lengths + sort_ind + nact ----------------
__global__ __launch_bounds__(128) void k_prep(const int* __restrict__ cap_len,
    const int* __restrict__ enc_caps, float* __restrict__ out,
    int* __restrict__ sort_i, int* __restrict__ decl_i, int* __restrict__ caps_i,
    int* __restrict__ nact_d){
  __shared__ int lens[B];
  __shared__ int sind[B];
  __shared__ int s_dl[B];
  int t = threadIdx.x;
  lens[t] = cap_len[t];
  __syncthreads();
  int my = lens[t];
  int rank = 0;
  for (int j=0;j<B;j++){
    int lj = lens[j];
    if (lj > my || (lj == my && j < t)) rank++;
  }
  sind[rank] = t;
  __syncthreads();
  int src = sind[t];
  sort_i[t] = src;
  int dl = lens[src]-1;
  decl_i[t] = dl;
  s_dl[t] = dl;
  out[OFF_DECL+t] = (float)dl;
  out[OFF_SORT+t] = (float)src;
  for (int j=0;j<CAPLEN;j++){
    int v = enc_caps[src*CAPLEN+j];
    caps_i[t*CAPLEN+j] = v;
    out[OFF_CAPS + t*CAPLEN + j] = (float)v;
  }
  __syncthreads();
  if (t < TT){
    int cnt = 0;
    for (int b2=0;b2<B;b2++) cnt += (s_dl[b2] > t) ? 1 : 0;
    nact_d[t] = cnt;
  }
}

// ---------------- mean over P of sorted encoder_out (f32) ----------------
__global__ __launch_bounds__(256) void k_mean(const float* __restrict__ enc,
    const int* __restrict__ sort_i, float* __restrict__ meanb){
  int b = blockIdx.x;
  int e = blockIdx.y*256 + threadIdx.x;
  int sb = sort_i[b];
  const float* p0 = enc + (size_t)sb*PP*ENC + e;
  float s = 0.f;
  for (int p=0;p<PP;p++) s += p0[(size_t)p*ENC];
  meanb[b*ENC+e] = s * (1.0f/PP);
}

// ---------------- h0/c0 f32 (one-time); h0 also -> xb bf16 ----------------
__global__ __launch_bounds__(256) void k_init(const float* __restrict__ meanb,
    const float* __restrict__ Wh, const float* __restrict__ bh,
    const float* __restrict__ Wc, const float* __restrict__ bc,
    float* __restrict__ h, float* __restrict__ c, ushort_t* __restrict__ xb_s){
  __shared__ float aT[64*132];
  __shared__ float wT[64*36];
  int tid = threadIdx.x;
  int n0 = blockIdx.x*32;
  const float* Wm  = blockIdx.y ? Wc : Wh;
  const float* bia = blockIdx.y ? bc : bh;
  float* dst = blockIdx.y ? c : h;
  int bt = tid&15, nt = tid>>4;
  float acc[8][2] = {};
  for (int k0=0;k0<ENC;k0+=64){
    for (int idx=tid; idx<64*128; idx+=256){
      int k=idx&63, m=idx>>6;
      aT[k*132+m] = meanb[m*ENC + k0+k];
    }
    for (int idx=tid; idx<64*32; idx+=256){
      int k=idx&63, n=idx>>6;
      wT[k*36+n] = Wm[(size_t)(n0+n)*ENC + k0+k];
    }
    __syncthreads();
    #pragma unroll 4
    for (int k=0;k<64;k++){
      float a[8], wv[2];
      *(float4*)&a[0] = *(const float4*)&aT[k*132+bt*8];
      *(float4*)&a[4] = *(const float4*)&aT[k*132+bt*8+4];
      *(float2*)&wv[0] = *(const float2*)&wT[k*36+nt*2];
      #pragma unroll
      for (int i=0;i<8;i++){ acc[i][0]+=a[i]*wv[0]; acc[i][1]+=a[i]*wv[1]; }
    }
    __syncthreads();
  }
  #pragma unroll
  for (int i=0;i<8;i++){
    int m = bt*8+i;
    #pragma unroll
    for (int j=0;j<2;j++){
      int n = n0+nt*2+j;
      float v = acc[i][j] + bia[n];
      dst[m*DEC+n] = v;
      if (blockIdx.y == 0) xb_s[(size_t)m*KPAD + n] = f2b(v);
    }
  }
}

// ---------------- weight converters (one-time) ----------------
__global__ __launch_bounds__(256) void k_wkb(const float* __restrict__ Whh,
    const float* __restrict__ Wih, uint_t* __restrict__ wkb_u){
  int n = blockIdx.x;
  uint_t* dst = wkb_u + (size_t)n*(KPAD/2);
  for (int u=threadIdx.x; u<KPAD/2; u+=256){
    int k = 2*u; float a, bvl;
    if (k < 512){ float2 v = *(const float2*)(Whh + (size_t)n*512 + k); a=v.x; bvl=v.y; }
    else if (k < 2860){ float2 v = *(const float2*)(Wih + (size_t)n*2348 + (k-512)); a=v.x; bvl=v.y; }
    else { a=0.f; bvl=0.f; }
    dst[u] = pack2(a, bvl);
  }
}
__global__ __launch_bounds__(256) void k_wcatb(const float* __restrict__ Wda,
    const float* __restrict__ Wfb, uint_t* __restrict__ wcat_u){
  int n = blockIdx.x;
  const float* src = (n < 512) ? (Wda + (size_t)n*512) : (Wfb + (size_t)(n-512)*512);
  uint_t* dst = wcat_u + (size_t)n*256;
  int u = threadIdx.x;
  float2 v = *(const float2*)(src + 2*u);
  dst[u] = pack2(v.x, v.y);
}
__global__ __launch_bounds__(256) void k_wfcb(const float* __restrict__ Wfc,
    uint_t* __restrict__ wfc_u){
  int n = blockIdx.x;
  uint_t* dst = wfc_u + (size_t)n*256;
  int u = threadIdx.x;
  if (n < VV){
    float2 v = *(const float2*)(Wfc + (size_t)n*512 + 2*u);
    dst[u] = pack2(v.x, v.y);
  } else dst[u] = 0u;
}
__global__ __launch_bounds__(256) void k_weab(const float* __restrict__ Wea,
    uint_t* __restrict__ wea_u){
  int n = blockIdx.x;
  uint_t* dst = wea_u + (size_t)n*1024;
  for (int u=threadIdx.x; u<1024; u+=256){
    float2 v = *(const float2*)(Wea + (size_t)n*2048 + 2*u);
    dst[u] = pack2(v.x, v.y);
  }
}
__global__ __launch_bounds__(160) void k_embb(const float* __restrict__ embedding,
    const int* __restrict__ caps_i, uint_t* __restrict__ embb_u){
  int b = blockIdx.x, t = blockIdx.y, tid = threadIdx.x;
  if (tid >= 150) return;
  int tok = caps_i[b*CAPLEN+t];
  float2 v = *(const float2*)(embedding + (size_t)tok*EMB + 2*tid);
  embb_u[((size_t)b*TT+t)*150 + tid] = pack2(v.x, v.y);
}
__global__ __launch_bounds__(256) void k_xpad(uint_t* __restrict__ xb_u){
  for (int u=threadIdx.x; u<1280; u+=256){
    int r = u/10, cu = u - r*10;
    xb_u[(size_t)r*(KPAD/2) + 1430 + cu] = 0u;
  }
}
__global__ __launch_bounds__(256) void k_encb(const float* __restrict__ enc,
    const int* __restrict__ sort_i, ushort_t* __restrict__ encb){
  int row = blockIdx.x;
  int b = row/PP, p = row - b*PP;
  int sb = sort_i[b];
  const float4* s4 = (const float4*)(enc + ((size_t)sb*PP+p)*ENC);
  uint4* d4 = (uint4*)(encb + (size_t)row*ENC);
  int tid = threadIdx.x;
  float4 f0 = s4[tid*2], f1 = s4[tid*2+1];
  uint4 q;
  q.x = pack2(f0.x,f0.y); q.y = pack2(f0.z,f0.w);
  q.z = pack2(f1.x,f1.y); q.w = pack2(f1.z,f1.w);
  d4[tid] = q;
}

// ---------------- one-time masked-zero writes for preds + alphas ----------------
__global__ __launch_bounds__(256) void k_zero(const int* __restrict__ decl_i,
    float* __restrict__ out){
  int blk = blockIdx.x;
  int b = blk/TT, t = blk - b*TT;
  if (t < decl_i[b]) return;
  float4 z = {0.f,0.f,0.f,0.f};
  float4* p = (float4*)(out + OFF_PRED + ((size_t)b*TT+t)*VV);
  for (int i=threadIdx.x; i<VV/4; i+=256) p[i] = z;
  size_t ao = (size_t)OFF_ALPH + ((size_t)b*TT+t)*PP;
  if (threadIdx.x < PP) out[ao + threadIdx.x] = 0.f;
}

// ---------------- one-time: att1 = encb @ Wea^T + bea -> attb (MFMA) ----------------
__global__ __launch_bounds__(256) void k_att1g(const ushort_t* __restrict__ encb,
    const ushort_t* __restrict__ weab, const float* __restrict__ bea,
    ushort_t* __restrict__ attb){
  __shared__ ushort_t As[128*40];
  __shared__ ushort_t Bs[64*40];
  int tid = threadIdx.x;
  int m0 = blockIdx.x*128, n0 = blockIdx.y*64;
  f4 acc[4][2] = {};
  gemm128x64(encb, 2048, m0, weab, 2048, n0, 0, 2048, 128, As, Bs, tid, acc);
  int w = tid>>6, l = tid&63, wm = w>>1, wn = w&1;
  #pragma unroll
  for (int fm=0; fm<4; fm++)
    #pragma unroll
    for (int fn=0; fn<2; fn++)
      #pragma unroll
      for (int rr=0; rr<4; rr++){
        int m = m0 + wm*64 + fm*16 + (l>>4)*4 + rr;
        int n = n0 + wn*32 + fn*16 + (l&15);
        attb[(size_t)m*ATTD + n] = f2b(acc[fm][fn][rr] + bea[n]);
      }
}

// ---------------- fallback one-time att1 (f32 VALU, no encb) ----------------
__global__ __launch_bounds__(256) void k_att1_f32(const float* __restrict__ enc,
    const float* __restrict__ Wea, const float* __restrict__ bea,
    const int* __restrict__ sort_i, ushort_t* __restrict__ attb){
  __shared__ float aT[64*132];
  __shared__ float wT[64*68];
  int tid = threadIdx.x;
  int m0 = blockIdx.x*128;
  int n0 = blockIdx.y*64;
  int bt = tid&15, nt = tid>>4;
  float acc[8][4] = {};
  for (int k0=0;k0<ENC;k0+=64){
    for (int idx=tid; idx<64*128; idx+=256){
      int k=idx&63, m=idx>>6;
      int mg = m0+m;
      int b = mg/PP; int p = mg - b*PP;
      int sb = sort_i[b];
      aT[k*132+m] = enc[((size_t)sb*PP + p)*ENC + k0+k];
    }
    for (int idx=tid; idx<64*64; idx+=256){
      int k=idx&63, n=idx>>6;
      wT[k*68+n] = Wea[(size_t)(n0+n)*ENC + k0+k];
    }
    __syncthreads();
    #pragma unroll 4
    for (int k=0;k<64;k++){
      float a[8], wv[4];
      *(float4*)&a[0] = *(const float4*)&aT[k*132+bt*8];
      *(float4*)&a[4] = *(const float4*)&aT[k*132+bt*8+4];
      *(float4*)&wv[0] = *(const float4*)&wT[k*68+nt*4];
      #pragma unroll
      for (int i=0;i<8;i++)
        #pragma unroll
        for (int j=0;j<4;j++) acc[i][j] += a[i]*wv[j];
    }
    __syncthreads();
  }
  #pragma unroll
  for (int i=0;i<8;i++){
    int mg = m0+bt*8+i;
    #pragma unroll
    for (int j=0;j<4;j++){
      int n = n0+nt*4+j;
      attb[(size_t)mg*ATTD + n] = f2b(acc[i][j] + bea[n]);
    }
  }
}

// ---------------- per-step: att2 + gate GEMM (MFMA) ----------------
__global__ __launch_bounds__(256) void k_hmats(const ushort_t* __restrict__ xb,
    const ushort_t* __restrict__ wcatb, const float* __restrict__ bda,
    const float* __restrict__ bfb, const int* __restrict__ nact_d,
    float* __restrict__ att2s, float* __restrict__ gate, int t){
  __shared__ ushort_t As[128*40];
  __shared__ ushort_t Bs[64*40];
  int tid = threadIdx.x;
  int n0 = blockIdx.x*64;
  int mb = nact_d[t];
  f4 acc[4][2] = {};
  gemm128x64(xb, KPAD, 0, wcatb, 512, n0, 0, 512, mb, As, Bs, tid, acc);
  int w = tid>>6, l = tid&63, wm = w>>1, wn = w&1;
  #pragma unroll
  for (int fm=0; fm<4; fm++)
    #pragma unroll
    for (int fn=0; fn<2; fn++)
      #pragma unroll
      for (int rr=0; rr<4; rr++){
        int m = wm*64 + fm*16 + (l>>4)*4 + rr;
        int n = n0 + wn*32 + fn*16 + (l&15);
        float v = acc[fm][fn][rr];
        if (n < 512) att2s[m*512+n] = v + bda[n];
        else         gate[m*2048 + (n-512)] = sigf(v + bfb[n-512]);
      }
}

// ---------------- per-step: score + softmax (+ emb->xb copy) ----------------
template<bool FULLT>
__global__ __launch_bounds__(512) void k_score(const ushort_t* __restrict__ attb,
    const float* __restrict__ att2s, const float* __restrict__ wfa,
    const float* __restrict__ bfa, const int* __restrict__ decl_i,
    float* __restrict__ alb, float* __restrict__ out,
    uint_t* __restrict__ xb_u, const uint_t* __restrict__ embb_u,
    const float* __restrict__ embedding, const int* __restrict__ caps_i, int t){
  int b = blockIdx.x, tid = threadIdx.x;
  if (t >= decl_i[b]) return;
  __shared__ float s_a2[512], s_w[512], s_sc[200], s_red[8], s_red2[8];
  if (FULLT){
    if (tid < 150) xb_u[b*(KPAD/2) + 256 + tid] = embb_u[((size_t)b*TT+t)*150 + tid];
  } else {
    if (tid < 150){
      int tok = caps_i[b*CAPLEN+t];
      float2 e = *(const float2*)(embedding + (size_t)tok*EMB + 2*tid);
      xb_u[b*(KPAD/2) + 256 + tid] = pack2(e.x, e.y);
    }
  }
  s_a2[tid] = att2s[b*512+tid];
  s_w[tid]  = wfa[tid];
  __syncthreads();
  int wid = tid>>6, lane = tid&63;
  float b0 = bfa[0];
  for (int p=wid; p<PP; p+=8){
    uint4 q = ((const uint4*)(attb + ((size_t)b*PP + p)*ATTD))[lane];
    int j = lane*8;
    float2 x0=b2x2(q.x), x1=b2x2(q.y), x2=b2x2(q.z), x3=b2x2(q.w);
    float s = fmaxf(x0.x+s_a2[j+0],0.f)*s_w[j+0] + fmaxf(x0.y+s_a2[j+1],0.f)*s_w[j+1]
            + fmaxf(x1.x+s_a2[j+2],0.f)*s_w[j+2] + fmaxf(x1.y+s_a2[j+3],0.f)*s_w[j+3]
            + fmaxf(x2.x+s_a2[j+4],0.f)*s_w[j+4] + fmaxf(x2.y+s_a2[j+5],0.f)*s_w[j+5]
            + fmaxf(x3.x+s_a2[j+6],0.f)*s_w[j+6] + fmaxf(x3.y+s_a2[j+7],0.f)*s_w[j+7];
    #pragma unroll
    for (int off=32;off;off>>=1) s += __shfl_down(s,off);
    if (lane==0) s_sc[p] = s + b0;
  }
  __syncthreads();
  float sc = (tid<PP) ? s_sc[tid] : -1e30f;
  float mx = sc;
  #pragma unroll
  for (int off=32;off;off>>=1) mx = fmaxf(mx, __shfl_down(mx,off));
  if (lane==0) s_red[wid] = mx;
  __syncthreads();
  mx = s_red[0];
  #pragma unroll
  for (int i=1;i<8;i++) mx = fmaxf(mx, s_red[i]);
  float e = (tid<PP) ? expf(sc-mx) : 0.f;
  float sm = e;
  #pragma unroll
  for (int off=32;off;off>>=1) sm += __shfl_down(sm,off);
  if (lane==0) s_red2[wid] = sm;
  __syncthreads();
  float tot = 0.f;
  #pragma unroll
  for (int i=0;i<8;i++) tot += s_red2[i];
  float inv = 1.f/tot;
  if (tid<PP){
    float al = e*inv;
    alb[b*PP+tid] = al;
    out[(size_t)OFF_ALPH + ((size_t)b*TT+t)*PP + tid] = al;
  }
}

// ---------------- per-step: awe (+ gate multiply) -> xb bf16 ----------------
template<bool ENCB_>
__global__ __launch_bounds__(256) void k_awe(const ushort_t* __restrict__ encb,
    const float* __restrict__ enc, const int* __restrict__ sort_i,
    const float* __restrict__ alb, const float* __restrict__ gate,
    const int* __restrict__ decl_i, uint_t* __restrict__ xb_u, int t){
  int b = blockIdx.x, seg = blockIdx.y, tid = threadIdx.x;
  if (t >= decl_i[b]) return;
  __shared__ float s_al[PP];
  if (tid < PP) s_al[tid] = alb[b*PP+tid];
  __syncthreads();
  int ch = seg*512 + tid*2;
  float a0=0.f, a1=0.f;
  if (ENCB_){
    const uint_t* E = (const uint_t*)encb + (size_t)b*PP*(ENC/2) + (ch>>1);
    #pragma unroll 4
    for (int p=0;p<PP;p++){
      float2 u = b2x2(E[(size_t)p*(ENC/2)]);
      float al = s_al[p];
      a0 += al*u.x; a1 += al*u.y;
    }
  } else {
    const float2* E = (const float2*)(enc + (size_t)sort_i[b]*PP*ENC + ch);
    #pragma unroll 4
    for (int p=0;p<PP;p++){
      float2 u = E[(size_t)p*(ENC/2)];
      float al = s_al[p];
      a0 += al*u.x; a1 += al*u.y;
    }
  }
  float g0 = gate[b*ENC+ch], g1 = gate[b*ENC+ch+1];
  xb_u[b*(KPAD/2) + 406 + seg*256 + tid] = pack2(a0*g0, a1*g1);
}

// ---------------- per-step: gates GEMM split-K (MFMA) ----------------
__global__ __launch_bounds__(256) void k_b1g(const ushort_t* __restrict__ xb,
    const ushort_t* __restrict__ wkb, const int* __restrict__ nact_d,
    float* __restrict__ pbuf, int t){
  __shared__ ushort_t As[128*40];
  __shared__ ushort_t Bs[64*40];
  int tid = threadIdx.x;
  int n0 = blockIdx.x*64;
  int s  = blockIdx.y;
  int Kb = s*736, Ke = min(KPAD, Kb+736);
  int mb = nact_d[t];
  f4 acc[4][2] = {};
  gemm128x64(xb, KPAD, 0, wkb, KPAD, n0, Kb, Ke, mb, As, Bs, tid, acc);
  int w = tid>>6, l = tid&63, wm = w>>1, wn = w&1;
  #pragma unroll
  for (int fm=0; fm<4; fm++)
    #pragma unroll
    for (int fn=0; fn<2; fn++)
      #pragma unroll
      for (int rr=0; rr<4; rr++){
        int m = wm*64 + fm*16 + (l>>4)*4 + rr;
        int n = n0 + wn*32 + fn*16 + (l&15);
        pbuf[((size_t)s*B + m)*2048 + n] = acc[fm][fn][rr];
      }
}

// ---------------- per-step: reduce + LSTM cell ----------------
__global__ __launch_bounds__(256) void k_b2(const float* __restrict__ pbuf,
    const float* __restrict__ b_ih, const float* __restrict__ b_hh,
    const int* __restrict__ decl_i, float* __restrict__ h, float* __restrict__ c,
    ushort_t* __restrict__ hnb, ushort_t* __restrict__ xb_s, int t){
  int b = blockIdx.x;
  int j = blockIdx.y*256 + threadIdx.x;
  float gi = b_ih[j]        + b_hh[j];
  float gf = b_ih[512+j]    + b_hh[512+j];
  float gg = b_ih[1024+j]   + b_hh[1024+j];
  float go = b_ih[1536+j]   + b_hh[1536+j];
  #pragma unroll
  for (int s=0;s<4;s++){
    const float* p = pbuf + ((size_t)s*B + b)*2048;
    gi += p[j]; gf += p[512+j]; gg += p[1024+j]; go += p[1536+j];
  }
  float hold = h[b*DEC+j];
  float cn = sigf(gf)*c[b*DEC+j] + sigf(gi)*tanhf(gg);
  float hn = sigf(go)*tanhf(cn);
  bool act = t < decl_i[b];
  if (act){ h[b*DEC+j] = hn; c[b*DEC+j] = cn; }
  hnb[b*DEC+j] = f2b(hn);
  xb_s[(size_t)b*KPAD + j] = f2b(act ? hn : hold);
}

// ---------------- per-step: preds GEMM (MFMA, active prefix only) ----------------
__global__ __launch_bounds__(256) void k_predg(const ushort_t* __restrict__ hnb,
    const ushort_t* __restrict__ wfcb, const float* __restrict__ b_fc,
    const int* __restrict__ nact_d, float* __restrict__ out, int t){
  __shared__ ushort_t As[128*40];
  __shared__ ushort_t Bs[64*40];
  int tid = threadIdx.x;
  int n0 = blockIdx.x*64;
  int mb = nact_d[t];
  f4 acc[4][2] = {};
  gemm128x64(hnb, 512, 0, wfcb, 512, n0, 0, 512, mb, As, Bs, tid, acc);
  int w = tid>>6, l = tid&63, wm = w>>1, wn = w&1;
  #pragma unroll
  for (int fm=0; fm<4; fm++)
    #pragma unroll
    for (int fn=0; fn<2; fn++)
      #pragma unroll
      for (int rr=0; rr<4; rr++){
        int m = wm*64 + fm*16 + (l>>4)*4 + rr;
        int n = n0 + wn*32 + fn*16 + (l&15);
        if (m < mb && n < VV)
          out[OFF_PRED + ((size_t)m*TT + t)*VV + n] = acc[fm][fn][rr] + b_fc[n];
      }
}

extern "C" void kernel_launch(void* const* d_in, const int* in_sizes, int n_in,
                              void* d_out, int out_size, void* d_ws, size_t ws_size,
                              hipStream_t stream){
  const float* enc       = (const float*)d_in[0];
  const int*   caps_in   = (const int*)d_in[1];
  const int*   caplen    = (const int*)d_in[2];
  const float* W_enc_att = (const float*)d_in[3];
  const float* b_enc_att = (const float*)d_in[4];
  const float* W_dec_att = (const float*)d_in[5];
  const float* b_dec_att = (const float*)d_in[6];
  const float* w_full_att= (const float*)d_in[7];
  const float* b_full_att= (const float*)d_in[8];
  const float* embedding = (const float*)d_in[9];
  const float* W_ih      = (const float*)d_in[10];
  const float* b_ih      = (const float*)d_in[11];
  const float* W_hh      = (const float*)d_in[12];
  const float* b_hh      = (const float*)d_in[13];
  const float* W_init_h  = (const float*)d_in[14];
  const float* b_init_h  = (const float*)d_in[15];
  const float* W_init_c  = (const float*)d_in[16];
  const float* b_init_c  = (const float*)d_in[17];
  const float* W_fbeta   = (const float*)d_in[18];
  const float* b_fbeta   = (const float*)d_in[19];
  const float* W_fc      = (const float*)d_in[20];
  const float* b_fc      = (const float*)d_in[21];
  float* out = (float*)d_out;

  float* W = (float*)d_ws;
  size_t o = 0;
  auto A = [&](size_t n){ float* p = W + o; o += n; return p; };

  bool FULL = ws_size >= 168000000ull;

  float* h      = A(65536);
  float* c      = A(65536);
  float* att2s  = A(65536);
  float* gate   = A(262144);
  float* alb    = A(25088);
  float* meanb  = A(262144);
  float* pbuf   = A(1048576);                      // 4 x 128 x 2048
  ushort_t* xb   = (ushort_t*)A(184320);           // 128 x 2880 bf16
  ushort_t* wkb  = (ushort_t*)A(2949120);          // 2048 x 2880 bf16
  ushort_t* wcatb= (ushort_t*)A(655360);           // 2560 x 512 bf16
  ushort_t* wfcb = (ushort_t*)A(2588672);          // 10112 x 512 bf16
  ushort_t* hnb  = (ushort_t*)A(32768);            // 128 x 512 bf16
  ushort_t* attb = (ushort_t*)A(6422528);          // 25088 x 512 bf16
  int* ip = (int*)A(6848);
  int* sort_i = ip;
  int* decl_i = ip + 128;
  int* nact_d = ip + 256;
  int* caps_i = ip + 320;
  ushort_t* weab = nullptr;
  uint_t*   embb_u = nullptr;
  ushort_t* encb = nullptr;
  if (FULL){
    weab   = (ushort_t*)A(524288);                 // 512 x 2048 bf16
    embb_u = (uint_t*)A(960000);                   // 128 x 50 x 300 bf16
    encb   = (ushort_t*)A(25690112);               // 25088 x 2048 bf16
  }
  uint_t* xb_u = (uint_t*)xb;

  k_prep<<<1,128,0,stream>>>(caplen, caps_in, out, sort_i, decl_i, caps_i, nact_d);
  k_mean<<<dim3(128,8),256,0,stream>>>(enc, sort_i, meanb);
  k_init<<<dim3(16,2),256,0,stream>>>(meanb, W_init_h, b_init_h, W_init_c, b_init_c, h, c, xb);
  k_wkb<<<2048,256,0,stream>>>(W_hh, W_ih, (uint_t*)wkb);
  k_wcatb<<<2560,256,0,stream>>>(W_dec_att, W_fbeta, (uint_t*)wcatb);
  k_wfcb<<<NPPAD,256,0,stream>>>(W_fc, (uint_t*)wfcb);
  k_xpad<<<1,256,0,stream>>>(xb_u);
  k_zero<<<6400,256,0,stream>>>(decl_i, out);
  if (FULL){
    k_weab<<<512,256,0,stream>>>(W_enc_att, (uint_t*)weab);
    k_embb<<<dim3(128,50),160,0,stream>>>(embedding, caps_i, embb_u);
    k_encb<<<25088,256,0,stream>>>(enc, sort_i, encb);
    k_att1g<<<dim3(196,8),256,0,stream>>>(encb, weab, b_enc_att, attb);
  } else {
    k_att1_f32<<<dim3(196,8),256,0,stream>>>(enc, W_enc_att, b_enc_att, sort_i, attb);
  }

  for (int t=0;t<TT;t++){
    k_hmats<<<40,256,0,stream>>>(xb, wcatb, b_dec_att, b_fbeta, nact_d, att2s, gate, t);
    if (FULL)
      k_score<true><<<128,512,0,stream>>>(attb, att2s, w_full_att, b_full_att, decl_i,
          alb, out, xb_u, embb_u, embedding, caps_i, t);
    else
      k_score<false><<<128,512,0,stream>>>(attb, att2s, w_full_att, b_full_att, decl_i,
          alb, out, xb_u, embb_u, embedding, caps_i, t);
    if (FULL)
      k_awe<true><<<dim3(128,4),256,0,stream>>>(encb, enc, sort_i, alb, gate, decl_i, xb_u, t);
    else
      k_awe<false><<<dim3(128,4),256,0,stream>>>(encb, enc, sort_i, alb, gate, decl_i, xb_u, t);
    k_b1g<<<dim3(32,4),256,0,stream>>>(xb, wkb, nact_d, pbuf, t);
    k_b2<<<dim3(128,2),256,0,stream>>>(pbuf, b_ih, b_hh, decl_i, h, c, hnb, xb, t);
    k_predg<<<158,256,0,stream>>>(hnb, wfcb, b_fc, nact_d, out, t);
  }
}